// Round 5
// baseline (691.151 us; speedup 1.0000x reference)
//
#include <hip/hip_runtime.h>
#include <stdint.h>

#define N_TOK    8192
#define DM       1024      // D_MODEL
#define DE       4096      // D_EXPERT
#define NEXP     8
#define CAP      2560
#define AUX_CO   0.01f
#define Z_CO     0.001f

typedef __attribute__((ext_vector_type(4))) float f32x4;
typedef __attribute__((ext_vector_type(8))) __bf16 bf16x8;

static __device__ __forceinline__ unsigned short f2bf(float f) {
  union { float f; uint32_t u; } v; v.f = f;
  uint32_t r = 0x7fffu + ((v.u >> 16) & 1u);
  return (unsigned short)((v.u + r) >> 16);
}
static __device__ __forceinline__ float bf2f(unsigned short u) {
  union { uint32_t u; float f; } v; v.u = ((uint32_t)u) << 16;
  return v.f;
}

#define MEMFENCE() asm volatile("" ::: "memory")
#define BAR()    do { MEMFENCE(); __builtin_amdgcn_s_barrier(); MEMFENCE(); } while (0)
#define LGKM0()  asm volatile("s_waitcnt lgkmcnt(0)" ::: "memory")
#define LGKM8()  asm volatile("s_waitcnt lgkmcnt(8)" ::: "memory")
#define VMW(N)   asm volatile("s_waitcnt vmcnt(" #N ")" ::: "memory")
#define SB0()    __builtin_amdgcn_sched_barrier(0)
#define GLD16(g, l) __builtin_amdgcn_global_load_lds( \
    (const __attribute__((address_space(1))) void*)(g), \
    (__attribute__((address_space(3))) void*)(l), 16, 0, 0)

// ---------------- init: inv map = -1 ----------------
__global__ void init_inv(int* __restrict__ inv) {
  int i = blockIdx.x * 256 + threadIdx.x;
  if (i < NEXP * CAP) inv[i] = -1;
}

// ------- transpose + fp32->bf16: in (R,C) -> out (C,R), per expert z (vectorized) -------
__global__ __launch_bounds__(256) void transpose_to_bf16(
    const float* __restrict__ in, unsigned short* __restrict__ out, int R, int C)
{
  __shared__ float tile[32][33];
  const size_t eoff = (size_t)blockIdx.z * R * C;
  const int bx = blockIdx.x * 32, by = blockIdx.y * 32;   // bx: C-dim, by: R-dim
  const int r = threadIdx.x >> 3, c4 = (threadIdx.x & 7) * 4;
  const float4 v = *(const float4*)&in[eoff + (size_t)(by + r) * C + bx + c4];
  tile[r][c4 + 0] = v.x; tile[r][c4 + 1] = v.y;
  tile[r][c4 + 2] = v.z; tile[r][c4 + 3] = v.w;
  __syncthreads();
  const int oc = threadIdx.x >> 3, r4 = (threadIdx.x & 7) * 4;
  ushort4 o;
  o.x = f2bf(tile[r4 + 0][oc]); o.y = f2bf(tile[r4 + 1][oc]);
  o.z = f2bf(tile[r4 + 2][oc]); o.w = f2bf(tile[r4 + 3][oc]);
  *(ushort4*)&out[eoff + (size_t)(bx + oc) * R + by + r4] = o;
}

// ---------------- router ----------------
__global__ __launch_bounds__(256) void router_kernel(
    const float* __restrict__ x, const float* __restrict__ Wr,
    int* __restrict__ topk, float* __restrict__ tkw, float* __restrict__ zP)
{
  const int tid = threadIdx.x, lane = tid & 63, wave = tid >> 6;
  float zacc = 0.f;
  float pacc[NEXP];
#pragma unroll
  for (int e = 0; e < NEXP; ++e) pacc[e] = 0.f;

  for (int it = 0; it < 4; ++it) {
    const int t = blockIdx.x * 16 + it * 4 + wave;
    float acc[NEXP];
#pragma unroll
    for (int e = 0; e < NEXP; ++e) acc[e] = 0.f;
    const f32x4* x4 = (const f32x4*)(x + (size_t)t * DM);
#pragma unroll
    for (int i = 0; i < 4; ++i) {
      f32x4 xv = x4[i * 64 + lane];
#pragma unroll
      for (int j = 0; j < 4; ++j) {
        const float xs = xv[j];
        const float* wr = Wr + (size_t)((i * 64 + lane) * 4 + j) * NEXP;
#pragma unroll
        for (int e = 0; e < NEXP; ++e) acc[e] += xs * wr[e];
      }
    }
#pragma unroll
    for (int m = 32; m; m >>= 1)
#pragma unroll
      for (int e = 0; e < NEXP; ++e) acc[e] += __shfl_xor(acc[e], m);

    float mx = acc[0];
#pragma unroll
    for (int e = 1; e < NEXP; ++e) mx = fmaxf(mx, acc[e]);
    float p[NEXP], s = 0.f;
#pragma unroll
    for (int e = 0; e < NEXP; ++e) { p[e] = expf(acc[e] - mx); s += p[e]; }
    const float lse = mx + logf(s);
    zacc += lse * lse;
    const float inv_s = 1.f / s;
#pragma unroll
    for (int e = 0; e < NEXP; ++e) pacc[e] += p[e] * inv_s;

    int e0 = 0; float v0 = p[0];
#pragma unroll
    for (int e = 1; e < NEXP; ++e) if (p[e] > v0) { v0 = p[e]; e0 = e; }
    int e1 = -1; float v1 = -1.f;
#pragma unroll
    for (int e = 0; e < NEXP; ++e) if (e != e0 && p[e] > v1) { v1 = p[e]; e1 = e; }

    const float pr0 = v0 * inv_s, pr1 = v1 * inv_s;
    const float denom = fmaxf(pr0 + pr1, 1e-9f);
    if (lane == 0) {
      topk[2*t]   = e0; topk[2*t+1] = e1;
      tkw[2*t]    = pr0 / denom; tkw[2*t+1] = pr1 / denom;
    }
  }
  __shared__ float blk[4][9];
  if (lane == 0) {
    blk[wave][0] = zacc;
#pragma unroll
    for (int e = 0; e < NEXP; ++e) blk[wave][1 + e] = pacc[e];
  }
  __syncthreads();
  if (tid < 9)
    zP[blockIdx.x * 9 + tid] = blk[0][tid] + blk[1][tid] + blk[2][tid] + blk[3][tid];
}

// ---------------- scan: FCFS capacity positions, wave per expert ----------------
__global__ __launch_bounds__(512) void scan_kernel(
    const int2* __restrict__ topk, const float2* __restrict__ tkw,
    int* __restrict__ posk, float* __restrict__ wts,
    int* __restrict__ inv, int* __restrict__ kept)
{
  const int lane = threadIdx.x & 63;
  const int e = threadIdx.x >> 6;           // 8 waves = 8 experts
  int base = 0;
  const uint64_t below = (lane == 63) ? 0xFFFFFFFFFFFFFFFFull >> 1
                                      : ((1ull << lane) - 1ull);
  for (int i = 0; i < N_TOK / 64; ++i) {
    const int t = i * 64 + lane;
    const int2 ti = topk[t];
    const float2 w = tkw[t];
    const bool hit = (ti.x == e) || (ti.y == e);
    const uint64_t m = __ballot(hit);
    if (hit) {
      const int pos = base + (int)__popcll(m & below);
      const bool kp = pos < CAP;
      const int k = (ti.x == e) ? 0 : 1;
      posk[2*t + k] = kp ? pos : CAP;
      wts[2*t + k]  = kp ? ((k == 0) ? w.x : w.y) : 0.f;
      if (kp) inv[e * CAP + pos] = t;
    }
    base += (int)__popcll(m);
  }
  if (lane == 0) kept[e] = base < CAP ? base : CAP;
}

// ---------------- dispatch ----------------
__global__ __launch_bounds__(256) void dispatch_kernel(
    const float* __restrict__ x, const int* __restrict__ inv,
    unsigned short* __restrict__ buf)
{
  const int slot = blockIdx.x;
  const int t = inv[slot];
  ushort4 o;
  if (t >= 0) {
    const f32x4 v = ((const f32x4*)(x + (size_t)t * DM))[threadIdx.x];
    o.x = f2bf(v[0]); o.y = f2bf(v[1]); o.z = f2bf(v[2]); o.w = f2bf(v[3]);
  } else {
    o.x = 0; o.y = 0; o.z = 0; o.w = 0;
  }
  ((ushort4*)(buf + (size_t)slot * DM))[threadIdx.x] = o;
}

// ================= 8-phase 256x256 grouped GEMM (m201 template port) =================
// C[e](M,N) = A[e](M,K) x Bt[e](N,K)^T + bias. BK=64 double-buffered; 4 phases/K-tile,
// one half-tile (2 x global_load_lds) staged per phase; vmcnt(4) once per K-tile.
// 8 waves (2M x 4N), per-wave output 128x64. XOR-swizzled LDS (measured 0 conflicts).
template<bool RELU>
__global__ __launch_bounds__(512, 2) void gemm256(
    const unsigned short* __restrict__ A,   // (E, M, K) bf16
    const unsigned short* __restrict__ Bt,  // (E, N, K) bf16
    const float* __restrict__ bias,         // (E, N)
    unsigned short* __restrict__ C,         // (E, M, N) bf16
    const int* __restrict__ kept,
    int M, int N, int K, int mt, int nt, int nwg)
{
  __shared__ __attribute__((aligned(16))) unsigned short As[2 * 256 * 64];
  __shared__ __attribute__((aligned(16))) unsigned short Bs[2 * 256 * 64];
  const int tid = threadIdx.x, lane = tid & 63, wave = tid >> 6;
  const int wr = wave >> 2, wc = wave & 3;          // 2M x 4N
  const int frow = lane & 15, kgrp = lane >> 4;

  int wg = (int)blockIdx.x;                         // bijective XCD chunking (nwg%8==0)
  wg = (wg & 7) * (nwg >> 3) + (wg >> 3);
  const int ntpe = mt * nt;
  const int e = wg / ntpe, rr = wg % ntpe;
  const int m0 = (rr / nt) * 256;
  const int n0 = (rr % nt) * 256;
  if (m0 >= kept[e]) return;                        // rows never read downstream

  const unsigned short* Ae = A  + (size_t)e * M * K + (size_t)m0 * K;
  const unsigned short* Be = Bt + (size_t)e * N * K + (size_t)n0 * K;

  const int srow = tid >> 3;                        // 0..63
  const int scol = ((tid & 7) ^ (srow & 7)) * 8;    // pre-swizzled source col (elems)

  // stage one half-tile (128 rows x 64 k) = 2 x global_load_lds(16B)
  auto stA = [&](int t, int h) {
    const int c = t & 1, k0 = t * 64;
#pragma unroll
    for (int i = 0; i < 2; ++i) {
      const int row = h * 128 + i * 64 + srow;
      GLD16(Ae + (size_t)row * K + (k0 + scol),
            &As[c * 16384 + (h * 128 + i * 64) * 64 + tid * 8]);
    }
  };
  auto stB = [&](int t, int h) {
    const int c = t & 1, k0 = t * 64;
#pragma unroll
    for (int i = 0; i < 2; ++i) {
      const int row = h * 128 + i * 64 + srow;
      GLD16(Be + (size_t)row * K + (k0 + scol),
            &Bs[c * 16384 + (h * 128 + i * 64) * 64 + tid * 8]);
    }
  };
  // register fragment reads (swizzled): A quad (4 m-frags x 2 kk), B pair (2 n-frags x 2 kk)
  auto rdA = [&](bf16x8* dst, int c, int mh) {
#pragma unroll
    for (int m = 0; m < 4; ++m) {
      const int row = wr * 128 + mh * 64 + m * 16 + frow;
#pragma unroll
      for (int kk = 0; kk < 2; ++kk)
        dst[m * 2 + kk] = *(const bf16x8*)
          &As[c * 16384 + row * 64 + ((kk * 4 + kgrp) ^ (row & 7)) * 8];
    }
  };
  auto rdB = [&](bf16x8* dst, int c, int nh) {
#pragma unroll
    for (int n = 0; n < 2; ++n) {
      const int row = wc * 64 + nh * 32 + n * 16 + frow;
#pragma unroll
      for (int kk = 0; kk < 2; ++kk)
        dst[n * 2 + kk] = *(const bf16x8*)
          &Bs[c * 16384 + row * 64 + ((kk * 4 + kgrp) ^ (row & 7)) * 8];
    }
  };

  f32x4 acc[8][4];
#pragma unroll
  for (int m = 0; m < 8; ++m)
#pragma unroll
    for (int n = 0; n < 4; ++n) acc[m][n] = (f32x4){0.f, 0.f, 0.f, 0.f};

  bf16x8 afA[8], bqA[4], bqB[4];

  auto mfma16 = [&](int mh, int nh, bf16x8* af, bf16x8* bq) {
#pragma unroll
    for (int m = 0; m < 4; ++m)
#pragma unroll
      for (int n = 0; n < 2; ++n)
#pragma unroll
        for (int kk = 0; kk < 2; ++kk)
          acc[mh * 4 + m][nh * 2 + n] = __builtin_amdgcn_mfma_f32_16x16x32_bf16(
              af[m * 2 + kk], bq[n * 2 + kk], acc[mh * 4 + m][nh * 2 + n], 0, 0, 0);
  };

  const int nk = K >> 6;   // >= 16 here

  // ---- prologue: A0h0 A0h1 B0h0 B0h1 B1h0 A1h0 in flight; tile0 (oldest 8 loads) landed ----
  stA(0, 0); stA(0, 1); stB(0, 0); stB(0, 1); stB(1, 0); stA(1, 0);
  VMW(4);
  BAR();

  for (int t = 0; t < nk; ++t) {
    const int c = t & 1;
    // ---- phase 1: read A(mh0)+B(nh0) [12 ds_read]; stage B(t+1)h1; MFMA q(0,0) ----
    rdB(bqA, c, 0);
    rdA(afA, c, 0);
    if (t + 1 < nk) stB(t + 1, 1);
    LGKM8();
    BAR(); LGKM0(); SB0();
    __builtin_amdgcn_s_setprio(1);
    mfma16(0, 0, afA, bqA);
    __builtin_amdgcn_s_setprio(0);
    BAR();
    // ---- phase 2: read B(nh1) [4]; stage A(t+1)h1; MFMA q(0,1) ----
    rdB(bqB, c, 1);
    if (t + 1 < nk) stA(t + 1, 1);
    BAR(); LGKM0(); SB0();
    __builtin_amdgcn_s_setprio(1);
    mfma16(0, 1, afA, bqB);
    __builtin_amdgcn_s_setprio(0);
    BAR();
    // ---- phase 3: read A(mh1) [8]; stage B(t+2)h0; MFMA q(1,0) ----
    rdA(afA, c, 1);
    if (t + 2 < nk) stB(t + 2, 0);
    BAR(); LGKM0(); SB0();
    __builtin_amdgcn_s_setprio(1);
    mfma16(1, 0, afA, bqA);
    __builtin_amdgcn_s_setprio(0);
    BAR();
    // ---- phase 4: stage A(t+2)h0; MFMA q(1,1); counted vmcnt; barrier ----
    if (t + 2 < nk) stA(t + 2, 0);
    BAR(); SB0();
    __builtin_amdgcn_s_setprio(1);
    mfma16(1, 1, afA, bqB);
    __builtin_amdgcn_s_setprio(0);
    if (t + 2 < nk)      { VMW(4); }
    else if (t + 1 < nk) { VMW(0); }
    if (t + 1 < nk) BAR();
  }

  // epilogue: D row = 4*kgrp + reg (m89/m91 layout), col = frow
  const int r0 = m0 + wr * 128 + 4 * kgrp;
  const int c0 = n0 + wc * 64 + frow;
#pragma unroll
  for (int nf = 0; nf < 4; ++nf) {
    const int cc = c0 + nf * 16;
    const float bv = bias[(size_t)e * N + cc];
#pragma unroll
    for (int m = 0; m < 8; ++m) {
#pragma unroll
      for (int r = 0; r < 4; ++r) {
        float v = acc[m][nf][r] + bv;
        if (RELU) v = fmaxf(v, 0.f);
        C[((size_t)e * M + (r0 + m * 16 + r)) * N + cc] = f2bf(v);
      }
    }
  }
}

// ---------------- combine ----------------
__global__ __launch_bounds__(256) void combine_kernel(
    const unsigned short* __restrict__ eo, const int* __restrict__ posk,
    const float* __restrict__ wts, const int* __restrict__ topk,
    float* __restrict__ out)
{
  const int t = blockIdx.x;
  const int e0 = topk[2*t], e1 = topk[2*t+1];
  int p0 = posk[2*t], p1 = posk[2*t+1];
  p0 = p0 < CAP - 1 ? p0 : CAP - 1;
  p1 = p1 < CAP - 1 ? p1 : CAP - 1;
  const float w0 = wts[2*t], w1 = wts[2*t+1];
  const ushort4 a = ((const ushort4*)(eo + ((size_t)e0 * CAP + p0) * DM))[threadIdx.x];
  const ushort4 b = ((const ushort4*)(eo + ((size_t)e1 * CAP + p1) * DM))[threadIdx.x];
  f32x4 o;
  o[0] = w0 * bf2f(a.x) + w1 * bf2f(b.x);
  o[1] = w0 * bf2f(a.y) + w1 * bf2f(b.y);
  o[2] = w0 * bf2f(a.z) + w1 * bf2f(b.z);
  o[3] = w0 * bf2f(a.w) + w1 * bf2f(b.w);
  ((f32x4*)(out + (size_t)t * DM))[threadIdx.x] = o;
}

// ---------------- finalize scalars ----------------
__global__ __launch_bounds__(64) void finalize_kernel(
    const float* __restrict__ zP, const int* __restrict__ kept,
    float* __restrict__ outs)
{
  const int lane = threadIdx.x;
  float v[9];
#pragma unroll
  for (int e = 0; e < 9; ++e) {
    float s = 0.f;
    for (int b = 0; b < 8; ++b) s += zP[(lane * 8 + b) * 9 + e];
    v[e] = s;
  }
#pragma unroll
  for (int m = 32; m; m >>= 1)
#pragma unroll
    for (int e = 0; e < 9; ++e) v[e] += __shfl_xor(v[e], m);
  if (lane == 0) {
    const float z = v[0] / (float)N_TOK;
    float total = 0.f;
    for (int e = 0; e < NEXP; ++e) total += (float)kept[e];
    total = fmaxf(total, 1.f);
    float aux = 0.f;
    for (int e = 0; e < NEXP; ++e)
      aux += ((float)kept[e] / total) * (v[1 + e] / (float)N_TOK);
    aux *= (float)NEXP;
    outs[0] = aux;
    outs[1] = z;
    outs[2] = AUX_CO * aux + Z_CO * z;
  }
}

extern "C" void kernel_launch(void* const* d_in, const int* in_sizes, int n_in,
                              void* d_out, int out_size, void* d_ws, size_t ws_size,
                              hipStream_t stream)
{
  const float* x  = (const float*)d_in[0];
  const float* Wr = (const float*)d_in[1];
  const float* W1 = (const float*)d_in[2];
  const float* b1 = (const float*)d_in[3];
  const float* W2 = (const float*)d_in[4];
  const float* b2 = (const float*)d_in[5];
  float* out = (float*)d_out;

  char* p = (char*)d_ws;
  auto alloc = [&](size_t bytes) {
    char* q = p; p += (bytes + 255) & ~(size_t)255; return q;
  };
  unsigned short* W1t = (unsigned short*)alloc((size_t)NEXP * DM * DE * 2);   // (E, DE, DM)
  unsigned short* W2t = (unsigned short*)alloc((size_t)NEXP * DM * DE * 2);   // (E, DM, DE)
  unsigned short* buf = (unsigned short*)alloc((size_t)NEXP * CAP * DM * 2);  // (E, cap, DM)
  unsigned short* h   = (unsigned short*)alloc((size_t)NEXP * CAP * DE * 2);  // (E, cap, DE)
  unsigned short* eo  = (unsigned short*)alloc((size_t)NEXP * CAP * DM * 2);  // (E, cap, DM)
  int*   topk = (int*)alloc((size_t)N_TOK * 2 * 4);
  float* tkw  = (float*)alloc((size_t)N_TOK * 2 * 4);
  int*   posk = (int*)alloc((size_t)N_TOK * 2 * 4);
  float* wts  = (float*)alloc((size_t)N_TOK * 2 * 4);
  int*   inv  = (int*)alloc((size_t)NEXP * CAP * 4);
  int*   kept = (int*)alloc((size_t)NEXP * 4);
  float* zP   = (float*)alloc((size_t)512 * 9 * 4);

  init_inv<<<(NEXP * CAP + 255) / 256, 256, 0, stream>>>(inv);
  transpose_to_bf16<<<dim3(DE / 32, DM / 32, NEXP), 256, 0, stream>>>(W1, W1t, DM, DE);
  transpose_to_bf16<<<dim3(DM / 32, DE / 32, NEXP), 256, 0, stream>>>(W2, W2t, DE, DM);
  router_kernel<<<512, 256, 0, stream>>>(x, Wr, topk, tkw, zP);
  scan_kernel<<<1, 512, 0, stream>>>((const int2*)topk, (const float2*)tkw, posk, wts, inv, kept);
  dispatch_kernel<<<NEXP * CAP, 256, 0, stream>>>(x, inv, buf);

  // GEMM1: (E,CAP,DM) x (E,DE,DM)^T -> (E,CAP,DE), ReLU. 10m x 16n x 8e = 1280 wgs.
  gemm256<true><<<1280, 512, 0, stream>>>(buf, W1t, b1, h, kept, CAP, DE, DM, 10, 16, 1280);
  // GEMM2: (E,CAP,DE) x (E,DM,DE)^T -> (E,CAP,DM). 10m x 4n x 8e = 320 wgs.
  gemm256<false><<<320, 512, 0, stream>>>(h, W2t, b2, eo, kept, CAP, DM, DE, 10, 4, 320);

  combine_kernel<<<N_TOK, 256, 0, stream>>>(eo, posk, wts, topk, out);
  finalize_kernel<<<1, 64, 0, stream>>>(zP, kept, out + (size_t)N_TOK * DM);
}

// Round 6
// 651.102 us; speedup vs baseline: 1.0615x; 1.0615x over previous
//
#include <hip/hip_runtime.h>
#include <stdint.h>

#define N_TOK    8192
#define DM       1024      // D_MODEL
#define DE       4096      // D_EXPERT
#define NEXP     8
#define CAP      2560
#define AUX_CO   0.01f
#define Z_CO     0.001f

typedef __attribute__((ext_vector_type(4))) float f32x4;
typedef __attribute__((ext_vector_type(8))) __bf16 bf16x8;

static __device__ __forceinline__ unsigned short f2bf(float f) {
  union { float f; uint32_t u; } v; v.f = f;
  uint32_t r = 0x7fffu + ((v.u >> 16) & 1u);
  return (unsigned short)((v.u + r) >> 16);
}
static __device__ __forceinline__ float bf2f(unsigned short u) {
  union { uint32_t u; float f; } v; v.u = ((uint32_t)u) << 16;
  return v.f;
}

#define GLD16(g, l) __builtin_amdgcn_global_load_lds( \
    (const __attribute__((address_space(1))) void*)(g), \
    (__attribute__((address_space(3))) void*)(l), 16, 0, 0)

// ---------------- init: inv map = -1 ----------------
__global__ void init_inv(int* __restrict__ inv) {
  int i = blockIdx.x * 256 + threadIdx.x;
  if (i < NEXP * CAP) inv[i] = -1;
}

// ------- transpose + fp32->bf16: in (R,C) -> out (C,R), per expert z (vectorized) -------
__global__ __launch_bounds__(256) void transpose_to_bf16(
    const float* __restrict__ in, unsigned short* __restrict__ out, int R, int C)
{
  __shared__ float tile[32][33];
  const size_t eoff = (size_t)blockIdx.z * R * C;
  const int bx = blockIdx.x * 32, by = blockIdx.y * 32;   // bx: C-dim, by: R-dim
  const int r = threadIdx.x >> 3, c4 = (threadIdx.x & 7) * 4;
  const float4 v = *(const float4*)&in[eoff + (size_t)(by + r) * C + bx + c4];
  tile[r][c4 + 0] = v.x; tile[r][c4 + 1] = v.y;
  tile[r][c4 + 2] = v.z; tile[r][c4 + 3] = v.w;
  __syncthreads();
  const int oc = threadIdx.x >> 3, r4 = (threadIdx.x & 7) * 4;
  ushort4 o;
  o.x = f2bf(tile[r4 + 0][oc]); o.y = f2bf(tile[r4 + 1][oc]);
  o.z = f2bf(tile[r4 + 2][oc]); o.w = f2bf(tile[r4 + 3][oc]);
  *(ushort4*)&out[eoff + (size_t)(bx + oc) * R + by + r4] = o;
}

// ---------------- router ----------------
__global__ __launch_bounds__(256) void router_kernel(
    const float* __restrict__ x, const float* __restrict__ Wr,
    int* __restrict__ topk, float* __restrict__ tkw, float* __restrict__ zP)
{
  const int tid = threadIdx.x, lane = tid & 63, wave = tid >> 6;
  float zacc = 0.f;
  float pacc[NEXP];
#pragma unroll
  for (int e = 0; e < NEXP; ++e) pacc[e] = 0.f;

  for (int it = 0; it < 4; ++it) {
    const int t = blockIdx.x * 16 + it * 4 + wave;
    float acc[NEXP];
#pragma unroll
    for (int e = 0; e < NEXP; ++e) acc[e] = 0.f;
    const f32x4* x4 = (const f32x4*)(x + (size_t)t * DM);
#pragma unroll
    for (int i = 0; i < 4; ++i) {
      f32x4 xv = x4[i * 64 + lane];
#pragma unroll
      for (int j = 0; j < 4; ++j) {
        const float xs = xv[j];
        const float* wr = Wr + (size_t)((i * 64 + lane) * 4 + j) * NEXP;
#pragma unroll
        for (int e = 0; e < NEXP; ++e) acc[e] += xs * wr[e];
      }
    }
#pragma unroll
    for (int m = 32; m; m >>= 1)
#pragma unroll
      for (int e = 0; e < NEXP; ++e) acc[e] += __shfl_xor(acc[e], m);

    float mx = acc[0];
#pragma unroll
    for (int e = 1; e < NEXP; ++e) mx = fmaxf(mx, acc[e]);
    float p[NEXP], s = 0.f;
#pragma unroll
    for (int e = 0; e < NEXP; ++e) { p[e] = expf(acc[e] - mx); s += p[e]; }
    const float lse = mx + logf(s);
    zacc += lse * lse;
    const float inv_s = 1.f / s;
#pragma unroll
    for (int e = 0; e < NEXP; ++e) pacc[e] += p[e] * inv_s;

    int e0 = 0; float v0 = p[0];
#pragma unroll
    for (int e = 1; e < NEXP; ++e) if (p[e] > v0) { v0 = p[e]; e0 = e; }
    int e1 = -1; float v1 = -1.f;
#pragma unroll
    for (int e = 0; e < NEXP; ++e) if (e != e0 && p[e] > v1) { v1 = p[e]; e1 = e; }

    const float pr0 = v0 * inv_s, pr1 = v1 * inv_s;
    const float denom = fmaxf(pr0 + pr1, 1e-9f);
    if (lane == 0) {
      topk[2*t]   = e0; topk[2*t+1] = e1;
      tkw[2*t]    = pr0 / denom; tkw[2*t+1] = pr1 / denom;
    }
  }
  __shared__ float blk[4][9];
  if (lane == 0) {
    blk[wave][0] = zacc;
#pragma unroll
    for (int e = 0; e < NEXP; ++e) blk[wave][1 + e] = pacc[e];
  }
  __syncthreads();
  if (tid < 9)
    zP[blockIdx.x * 9 + tid] = blk[0][tid] + blk[1][tid] + blk[2][tid] + blk[3][tid];
}

// ---------------- scan: FCFS capacity positions, wave per expert ----------------
__global__ __launch_bounds__(512) void scan_kernel(
    const int2* __restrict__ topk, const float2* __restrict__ tkw,
    int* __restrict__ posk, float* __restrict__ wts,
    int* __restrict__ inv, int* __restrict__ kept)
{
  const int lane = threadIdx.x & 63;
  const int e = threadIdx.x >> 6;           // 8 waves = 8 experts
  int base = 0;
  const uint64_t below = (lane == 63) ? 0xFFFFFFFFFFFFFFFFull >> 1
                                      : ((1ull << lane) - 1ull);
  for (int i = 0; i < N_TOK / 64; ++i) {
    const int t = i * 64 + lane;
    const int2 ti = topk[t];
    const float2 w = tkw[t];
    const bool hit = (ti.x == e) || (ti.y == e);
    const uint64_t m = __ballot(hit);
    if (hit) {
      const int pos = base + (int)__popcll(m & below);
      const bool kp = pos < CAP;
      const int k = (ti.x == e) ? 0 : 1;
      posk[2*t + k] = kp ? pos : CAP;
      wts[2*t + k]  = kp ? ((k == 0) ? w.x : w.y) : 0.f;
      if (kp) inv[e * CAP + pos] = t;
    }
    base += (int)__popcll(m);
  }
  if (lane == 0) kept[e] = base < CAP ? base : CAP;
}

// ---------------- dispatch ----------------
__global__ __launch_bounds__(256) void dispatch_kernel(
    const float* __restrict__ x, const int* __restrict__ inv,
    unsigned short* __restrict__ buf)
{
  const int slot = blockIdx.x;
  const int t = inv[slot];
  ushort4 o;
  if (t >= 0) {
    const f32x4 v = ((const f32x4*)(x + (size_t)t * DM))[threadIdx.x];
    o.x = f2bf(v[0]); o.y = f2bf(v[1]); o.z = f2bf(v[2]); o.w = f2bf(v[3]);
  } else {
    o.x = 0; o.y = 0; o.z = 0; o.w = 0;
  }
  ((ushort4*)(buf + (size_t)slot * DM))[threadIdx.x] = o;
}

// ========== 2-phase dbuf grouped GEMM (round-4 gemmB structure, templated) ==========
// C[e](M,N) = A[e](M,K) x Bt[e](N,K)^T + bias. BK=64 double-buffered; stage(t+1)
// issued BEFORE compute(t) so HBM hides under MFMA; compiler-managed syncthreads.
// 8 waves (2M x 4N). XOR-swizzled LDS (measured: 0 bank conflicts).
template<int BM, int BN, bool RELU>
__global__ __launch_bounds__(512, (BM == 256) ? 2 : 4) void gemm2p(
    const unsigned short* __restrict__ A,   // (E, M, K) bf16
    const unsigned short* __restrict__ Bt,  // (E, N, K) bf16
    const float* __restrict__ bias,         // (E, N)
    unsigned short* __restrict__ C,         // (E, M, N) bf16
    const int* __restrict__ kept,
    int M, int N, int K, int mt, int nt, int nwg)
{
  constexpr int MF = BM / 32;               // m-frags per wave (8 / 4)
  constexpr int NF = BN / 64;               // n-frags per wave (4 / 2)
  constexpr int ABUF = BM * 64;             // elems per A buffer
  constexpr int BBUF = BN * 64;
  __shared__ __attribute__((aligned(16))) unsigned short As[2 * ABUF];
  __shared__ __attribute__((aligned(16))) unsigned short Bs[2 * BBUF];

  const int tid = threadIdx.x, lane = tid & 63, wave = tid >> 6;
  const int wr = wave >> 2, wc = wave & 3;  // 2M x 4N
  const int frow = lane & 15, kgrp = lane >> 4;

  int wg = (int)blockIdx.x;                 // bijective XCD chunking (nwg%8==0)
  wg = (wg & 7) * (nwg >> 3) + (wg >> 3);
  const int ntpe = mt * nt;
  const int e = wg / ntpe, rr = wg % ntpe;
  const int m0 = (rr / nt) * BM;
  const int n0 = (rr % nt) * BN;
  if (m0 >= kept[e]) return;                // rows never read downstream

  const unsigned short* Ae = A  + (size_t)e * M * K + (size_t)m0 * K;
  const unsigned short* Be = Bt + (size_t)e * N * K + (size_t)n0 * K;

  const int srow = tid >> 3;                        // 0..63
  const int scol = ((tid & 7) ^ (srow & 7)) * 8;    // pre-swizzled source col (elems)

  auto stage = [&](int buf, int k0) {
#pragma unroll
    for (int i = 0; i < BM / 64; ++i)
      GLD16(Ae + (size_t)(i * 64 + srow) * K + (k0 + scol),
            &As[buf * ABUF + i * 4096 + tid * 8]);
#pragma unroll
    for (int i = 0; i < BN / 64; ++i)
      GLD16(Be + (size_t)(i * 64 + srow) * K + (k0 + scol),
            &Bs[buf * BBUF + i * 4096 + tid * 8]);
  };

  f32x4 acc[MF][NF];
#pragma unroll
  for (int m = 0; m < MF; ++m)
#pragma unroll
    for (int n = 0; n < NF; ++n) acc[m][n] = (f32x4){0.f, 0.f, 0.f, 0.f};

  const int nk = K >> 6;
  stage(0, 0);
  for (int t = 0; t < nk; ++t) {
    const int cur = t & 1;
    __syncthreads();                 // stage(t) landed; prior reads of buf cur^1 done
    if (t + 1 < nk) stage(cur ^ 1, (t + 1) * 64);
#pragma unroll
    for (int kk = 0; kk < 2; ++kk) {
      bf16x8 bq[NF], af[MF];
#pragma unroll
      for (int n = 0; n < NF; ++n) {
        const int row = wc * (BN / 4) + n * 16 + frow;
        const int slot = (kk * 4 + kgrp) ^ (row & 7);
        bq[n] = *(const bf16x8*)&Bs[cur * BBUF + row * 64 + slot * 8];
      }
#pragma unroll
      for (int m = 0; m < MF; ++m) {
        const int row = wr * (BM / 2) + m * 16 + frow;
        const int slot = (kk * 4 + kgrp) ^ (row & 7);
        af[m] = *(const bf16x8*)&As[cur * ABUF + row * 64 + slot * 8];
      }
      __builtin_amdgcn_s_setprio(1);
#pragma unroll
      for (int m = 0; m < MF; ++m)
#pragma unroll
        for (int n = 0; n < NF; ++n)
          acc[m][n] = __builtin_amdgcn_mfma_f32_16x16x32_bf16(af[m], bq[n], acc[m][n], 0, 0, 0);
      __builtin_amdgcn_s_setprio(0);
    }
  }

  // epilogue: D row = 4*kgrp + reg (m89/m91 layout), col = frow
  const int r0 = m0 + wr * (BM / 2) + 4 * kgrp;
  const int c0 = n0 + wc * (BN / 4) + frow;
#pragma unroll
  for (int n = 0; n < NF; ++n) {
    const int cc = c0 + n * 16;
    const float bv = bias[(size_t)e * N + cc];
#pragma unroll
    for (int m = 0; m < MF; ++m) {
#pragma unroll
      for (int r = 0; r < 4; ++r) {
        float v = acc[m][n][r] + bv;
        if (RELU) v = fmaxf(v, 0.f);
        C[((size_t)e * M + (r0 + m * 16 + r)) * N + cc] = f2bf(v);
      }
    }
  }
}

// ---------------- combine ----------------
__global__ __launch_bounds__(256) void combine_kernel(
    const unsigned short* __restrict__ eo, const int* __restrict__ posk,
    const float* __restrict__ wts, const int* __restrict__ topk,
    float* __restrict__ out)
{
  const int t = blockIdx.x;
  const int e0 = topk[2*t], e1 = topk[2*t+1];
  int p0 = posk[2*t], p1 = posk[2*t+1];
  p0 = p0 < CAP - 1 ? p0 : CAP - 1;
  p1 = p1 < CAP - 1 ? p1 : CAP - 1;
  const float w0 = wts[2*t], w1 = wts[2*t+1];
  const ushort4 a = ((const ushort4*)(eo + ((size_t)e0 * CAP + p0) * DM))[threadIdx.x];
  const ushort4 b = ((const ushort4*)(eo + ((size_t)e1 * CAP + p1) * DM))[threadIdx.x];
  f32x4 o;
  o[0] = w0 * bf2f(a.x) + w1 * bf2f(b.x);
  o[1] = w0 * bf2f(a.y) + w1 * bf2f(b.y);
  o[2] = w0 * bf2f(a.z) + w1 * bf2f(b.z);
  o[3] = w0 * bf2f(a.w) + w1 * bf2f(b.w);
  ((f32x4*)(out + (size_t)t * DM))[threadIdx.x] = o;
}

// ---------------- finalize scalars ----------------
__global__ __launch_bounds__(64) void finalize_kernel(
    const float* __restrict__ zP, const int* __restrict__ kept,
    float* __restrict__ outs)
{
  const int lane = threadIdx.x;
  float v[9];
#pragma unroll
  for (int e = 0; e < 9; ++e) {
    float s = 0.f;
    for (int b = 0; b < 8; ++b) s += zP[(lane * 8 + b) * 9 + e];
    v[e] = s;
  }
#pragma unroll
  for (int m = 32; m; m >>= 1)
#pragma unroll
    for (int e = 0; e < 9; ++e) v[e] += __shfl_xor(v[e], m);
  if (lane == 0) {
    const float z = v[0] / (float)N_TOK;
    float total = 0.f;
    for (int e = 0; e < NEXP; ++e) total += (float)kept[e];
    total = fmaxf(total, 1.f);
    float aux = 0.f;
    for (int e = 0; e < NEXP; ++e)
      aux += ((float)kept[e] / total) * (v[1 + e] / (float)N_TOK);
    aux *= (float)NEXP;
    outs[0] = aux;
    outs[1] = z;
    outs[2] = AUX_CO * aux + Z_CO * z;
  }
}

extern "C" void kernel_launch(void* const* d_in, const int* in_sizes, int n_in,
                              void* d_out, int out_size, void* d_ws, size_t ws_size,
                              hipStream_t stream)
{
  const float* x  = (const float*)d_in[0];
  const float* Wr = (const float*)d_in[1];
  const float* W1 = (const float*)d_in[2];
  const float* b1 = (const float*)d_in[3];
  const float* W2 = (const float*)d_in[4];
  const float* b2 = (const float*)d_in[5];
  float* out = (float*)d_out;

  char* p = (char*)d_ws;
  auto alloc = [&](size_t bytes) {
    char* q = p; p += (bytes + 255) & ~(size_t)255; return q;
  };
  unsigned short* W1t = (unsigned short*)alloc((size_t)NEXP * DM * DE * 2);   // (E, DE, DM)
  unsigned short* W2t = (unsigned short*)alloc((size_t)NEXP * DM * DE * 2);   // (E, DM, DE)
  unsigned short* buf = (unsigned short*)alloc((size_t)NEXP * CAP * DM * 2);  // (E, cap, DM)
  unsigned short* h   = (unsigned short*)alloc((size_t)NEXP * CAP * DE * 2);  // (E, cap, DE)
  unsigned short* eo  = (unsigned short*)alloc((size_t)NEXP * CAP * DM * 2);  // (E, cap, DM)
  int*   topk = (int*)alloc((size_t)N_TOK * 2 * 4);
  float* tkw  = (float*)alloc((size_t)N_TOK * 2 * 4);
  int*   posk = (int*)alloc((size_t)N_TOK * 2 * 4);
  float* wts  = (float*)alloc((size_t)N_TOK * 2 * 4);
  int*   inv  = (int*)alloc((size_t)NEXP * CAP * 4);
  int*   kept = (int*)alloc((size_t)NEXP * 4);
  float* zP   = (float*)alloc((size_t)512 * 9 * 4);

  init_inv<<<(NEXP * CAP + 255) / 256, 256, 0, stream>>>(inv);
  transpose_to_bf16<<<dim3(DE / 32, DM / 32, NEXP), 256, 0, stream>>>(W1, W1t, DM, DE);
  transpose_to_bf16<<<dim3(DM / 32, DE / 32, NEXP), 256, 0, stream>>>(W2, W2t, DE, DM);
  router_kernel<<<512, 256, 0, stream>>>(x, Wr, topk, tkw, zP);
  scan_kernel<<<1, 512, 0, stream>>>((const int2*)topk, (const float2*)tkw, posk, wts, inv, kept);
  dispatch_kernel<<<NEXP * CAP, 256, 0, stream>>>(x, inv, buf);

  // GEMM1: (E,CAP,DM) x (E,DE,DM)^T -> (E,CAP,DE), ReLU.
  // 256x256 tiles: 10m x 16n x 8e = 1280 wgs = exactly 5 blocks/CU (balanced).
  gemm2p<256, 256, true><<<1280, 512, 0, stream>>>(
      buf, W1t, b1, h, kept, CAP, DE, DM, 10, 16, 1280);
  // GEMM2: (E,CAP,DE) x (E,DM,DE)^T -> (E,CAP,DM).
  // 128x128 tiles (64KB LDS -> 2 blocks/CU): 20m x 8n x 8e = 1280 wgs, 5/CU.
  gemm2p<128, 128, false><<<1280, 512, 0, stream>>>(
      h, W2t, b2, eo, kept, CAP, DM, DE, 20, 8, 1280);

  combine_kernel<<<N_TOK, 256, 0, stream>>>(eo, posk, wts, topk, out);
  finalize_kernel<<<1, 64, 0, stream>>>(zP, kept, out + (size_t)N_TOK * DM);
}

// Round 7
// 592.700 us; speedup vs baseline: 1.1661x; 1.0985x over previous
//
#include <hip/hip_runtime.h>
#include <stdint.h>

#define N_TOK    8192
#define DM       1024      // D_MODEL
#define DE       4096      // D_EXPERT
#define NEXP     8
#define CAP      2560
#define AUX_CO   0.01f
#define Z_CO     0.001f

typedef __attribute__((ext_vector_type(4))) float f32x4;
typedef __attribute__((ext_vector_type(8))) __bf16 bf16x8;

static __device__ __forceinline__ unsigned short f2bf(float f) {
  union { float f; uint32_t u; } v; v.f = f;
  uint32_t r = 0x7fffu + ((v.u >> 16) & 1u);
  return (unsigned short)((v.u + r) >> 16);
}
static __device__ __forceinline__ float bf2f(unsigned short u) {
  union { uint32_t u; float f; } v; v.u = ((uint32_t)u) << 16;
  return v.f;
}

#define MEMFENCE() asm volatile("" ::: "memory")
#define BAR()    do { MEMFENCE(); __builtin_amdgcn_s_barrier(); MEMFENCE(); } while (0)
#define LGKM0()  asm volatile("s_waitcnt lgkmcnt(0)" ::: "memory")
#define LGKM8()  asm volatile("s_waitcnt lgkmcnt(8)" ::: "memory")
#define VMW(N)   asm volatile("s_waitcnt vmcnt(" #N ")" ::: "memory")
#define SB0()    __builtin_amdgcn_sched_barrier(0)
#define GLD16(g, l) __builtin_amdgcn_global_load_lds( \
    (const __attribute__((address_space(1))) void*)(g), \
    (__attribute__((address_space(3))) void*)(l), 16, 0, 0)

// ------- transpose + fp32->bf16: in (R,C) -> out (C,R), per expert z (vectorized) -------
__global__ __launch_bounds__(256) void transpose_to_bf16(
    const float* __restrict__ in, unsigned short* __restrict__ out, int R, int C)
{
  __shared__ float tile[32][33];
  const size_t eoff = (size_t)blockIdx.z * R * C;
  const int bx = blockIdx.x * 32, by = blockIdx.y * 32;   // bx: C-dim, by: R-dim
  const int r = threadIdx.x >> 3, c4 = (threadIdx.x & 7) * 4;
  const float4 v = *(const float4*)&in[eoff + (size_t)(by + r) * C + bx + c4];
  tile[r][c4 + 0] = v.x; tile[r][c4 + 1] = v.y;
  tile[r][c4 + 2] = v.z; tile[r][c4 + 3] = v.w;
  __syncthreads();
  const int oc = threadIdx.x >> 3, r4 = (threadIdx.x & 7) * 4;
  ushort4 o;
  o.x = f2bf(tile[r4 + 0][oc]); o.y = f2bf(tile[r4 + 1][oc]);
  o.z = f2bf(tile[r4 + 2][oc]); o.w = f2bf(tile[r4 + 3][oc]);
  *(ushort4*)&out[eoff + (size_t)(bx + oc) * R + by + r4] = o;
}

// ---------------- router ----------------
__global__ __launch_bounds__(256) void router_kernel(
    const float* __restrict__ x, const float* __restrict__ Wr,
    int* __restrict__ topk, float* __restrict__ tkw, float* __restrict__ zP)
{
  const int tid = threadIdx.x, lane = tid & 63, wave = tid >> 6;
  float zacc = 0.f;
  float pacc[NEXP];
#pragma unroll
  for (int e = 0; e < NEXP; ++e) pacc[e] = 0.f;

  for (int it = 0; it < 4; ++it) {
    const int t = blockIdx.x * 16 + it * 4 + wave;
    float acc[NEXP];
#pragma unroll
    for (int e = 0; e < NEXP; ++e) acc[e] = 0.f;
    const f32x4* x4 = (const f32x4*)(x + (size_t)t * DM);
#pragma unroll
    for (int i = 0; i < 4; ++i) {
      f32x4 xv = x4[i * 64 + lane];
#pragma unroll
      for (int j = 0; j < 4; ++j) {
        const float xs = xv[j];
        const float* wr = Wr + (size_t)((i * 64 + lane) * 4 + j) * NEXP;
#pragma unroll
        for (int e = 0; e < NEXP; ++e) acc[e] += xs * wr[e];
      }
    }
#pragma unroll
    for (int m = 32; m; m >>= 1)
#pragma unroll
      for (int e = 0; e < NEXP; ++e) acc[e] += __shfl_xor(acc[e], m);

    float mx = acc[0];
#pragma unroll
    for (int e = 1; e < NEXP; ++e) mx = fmaxf(mx, acc[e]);
    float p[NEXP], s = 0.f;
#pragma unroll
    for (int e = 0; e < NEXP; ++e) { p[e] = expf(acc[e] - mx); s += p[e]; }
    const float lse = mx + logf(s);
    zacc += lse * lse;
    const float inv_s = 1.f / s;
#pragma unroll
    for (int e = 0; e < NEXP; ++e) pacc[e] += p[e] * inv_s;

    int e0 = 0; float v0 = p[0];
#pragma unroll
    for (int e = 1; e < NEXP; ++e) if (p[e] > v0) { v0 = p[e]; e0 = e; }
    int e1 = -1; float v1 = -1.f;
#pragma unroll
    for (int e = 0; e < NEXP; ++e) if (e != e0 && p[e] > v1) { v1 = p[e]; e1 = e; }

    const float pr0 = v0 * inv_s, pr1 = v1 * inv_s;
    const float denom = fmaxf(pr0 + pr1, 1e-9f);
    if (lane == 0) {
      topk[2*t]   = e0; topk[2*t+1] = e1;
      tkw[2*t]    = pr0 / denom; tkw[2*t+1] = pr1 / denom;
    }
  }
  __shared__ float blk[4][9];
  if (lane == 0) {
    blk[wave][0] = zacc;
#pragma unroll
    for (int e = 0; e < NEXP; ++e) blk[wave][1 + e] = pacc[e];
  }
  __syncthreads();
  if (tid < 9)
    zP[blockIdx.x * 9 + tid] = blk[0][tid] + blk[1][tid] + blk[2][tid] + blk[3][tid];
}

// -------- scan: FCFS capacity positions; topk/tkw staged in LDS (kills the serial
// -------- global-load latency chain); inv tail-fill fused (replaces init_inv) --------
__global__ __launch_bounds__(512) void scan_kernel(
    const int2* __restrict__ topk, const float2* __restrict__ tkw,
    int* __restrict__ posk, float* __restrict__ wts,
    int* __restrict__ inv, int* __restrict__ kept)
{
  __shared__ int2   stopk[N_TOK];
  __shared__ float2 stkw[N_TOK];
  const int tid = threadIdx.x;
  for (int j = tid; j < N_TOK; j += 512) { stopk[j] = topk[j]; stkw[j] = tkw[j]; }
  __syncthreads();

  const int lane = tid & 63;
  const int e = tid >> 6;                   // 8 waves = 8 experts
  int base = 0;
  const uint64_t below = (lane == 63) ? 0xFFFFFFFFFFFFFFFFull >> 1
                                      : ((1ull << lane) - 1ull);
  for (int i = 0; i < N_TOK / 64; ++i) {
    const int t = i * 64 + lane;
    const int2 ti = stopk[t];
    const float2 w = stkw[t];
    const bool hit = (ti.x == e) || (ti.y == e);
    const uint64_t m = __ballot(hit);
    if (hit) {
      const int pos = base + (int)__popcll(m & below);
      const bool kp = pos < CAP;
      const int k = (ti.x == e) ? 0 : 1;
      posk[2*t + k] = kp ? pos : CAP;
      wts[2*t + k]  = kp ? ((k == 0) ? w.x : w.y) : 0.f;
      if (kp) inv[e * CAP + pos] = t;
    }
    base += (int)__popcll(m);
  }
  const int tail = base < CAP ? base : CAP;
  for (int q = tail + lane; q < CAP; q += 64) inv[e * CAP + q] = -1;
  if (lane == 0) kept[e] = tail;
}

// ---------------- dispatch ----------------
__global__ __launch_bounds__(256) void dispatch_kernel(
    const float* __restrict__ x, const int* __restrict__ inv,
    unsigned short* __restrict__ buf)
{
  const int slot = blockIdx.x;
  const int t = inv[slot];
  ushort4 o;
  if (t >= 0) {
    const f32x4 v = ((const f32x4*)(x + (size_t)t * DM))[threadIdx.x];
    o.x = f2bf(v[0]); o.y = f2bf(v[1]); o.z = f2bf(v[2]); o.w = f2bf(v[3]);
  } else {
    o.x = 0; o.y = 0; o.z = 0; o.w = 0;
  }
  ((ushort4*)(buf + (size_t)slot * DM))[threadIdx.x] = o;
}

// ========== 2-phase dbuf grouped GEMM (proven ~685 TF; keeper for GEMM2) ==========
template<int BM, int BN, bool RELU>
__global__ __launch_bounds__(512, (BM == 256) ? 2 : 4) void gemm2p(
    const unsigned short* __restrict__ A,   // (E, M, K) bf16
    const unsigned short* __restrict__ Bt,  // (E, N, K) bf16
    const float* __restrict__ bias,         // (E, N)
    unsigned short* __restrict__ C,         // (E, M, N) bf16
    const int* __restrict__ kept,
    int M, int N, int K, int mt, int nt, int nwg)
{
  constexpr int MF = BM / 32;
  constexpr int NF = BN / 64;
  constexpr int ABUF = BM * 64;
  constexpr int BBUF = BN * 64;
  __shared__ __attribute__((aligned(16))) unsigned short As[2 * ABUF];
  __shared__ __attribute__((aligned(16))) unsigned short Bs[2 * BBUF];

  const int tid = threadIdx.x, lane = tid & 63, wave = tid >> 6;
  const int wr = wave >> 2, wc = wave & 3;  // 2M x 4N
  const int frow = lane & 15, kgrp = lane >> 4;

  int wg = (int)blockIdx.x;                 // bijective XCD chunking (nwg%8==0)
  wg = (wg & 7) * (nwg >> 3) + (wg >> 3);
  const int ntpe = mt * nt;
  const int e = wg / ntpe, rr = wg % ntpe;
  const int m0 = (rr / nt) * BM;
  const int n0 = (rr % nt) * BN;
  if (m0 >= kept[e]) return;

  const unsigned short* Ae = A  + (size_t)e * M * K + (size_t)m0 * K;
  const unsigned short* Be = Bt + (size_t)e * N * K + (size_t)n0 * K;

  const int srow = tid >> 3;
  const int scol = ((tid & 7) ^ (srow & 7)) * 8;

  auto stage = [&](int buf, int k0) {
#pragma unroll
    for (int i = 0; i < BM / 64; ++i)
      GLD16(Ae + (size_t)(i * 64 + srow) * K + (k0 + scol),
            &As[buf * ABUF + i * 4096 + tid * 8]);
#pragma unroll
    for (int i = 0; i < BN / 64; ++i)
      GLD16(Be + (size_t)(i * 64 + srow) * K + (k0 + scol),
            &Bs[buf * BBUF + i * 4096 + tid * 8]);
  };

  f32x4 acc[MF][NF];
#pragma unroll
  for (int m = 0; m < MF; ++m)
#pragma unroll
    for (int n = 0; n < NF; ++n) acc[m][n] = (f32x4){0.f, 0.f, 0.f, 0.f};

  const int nk = K >> 6;
  stage(0, 0);
  for (int t = 0; t < nk; ++t) {
    const int cur = t & 1;
    __syncthreads();
    if (t + 1 < nk) stage(cur ^ 1, (t + 1) * 64);
#pragma unroll
    for (int kk = 0; kk < 2; ++kk) {
      bf16x8 bq[NF], af[MF];
#pragma unroll
      for (int n = 0; n < NF; ++n) {
        const int row = wc * (BN / 4) + n * 16 + frow;
        const int slot = (kk * 4 + kgrp) ^ (row & 7);
        bq[n] = *(const bf16x8*)&Bs[cur * BBUF + row * 64 + slot * 8];
      }
#pragma unroll
      for (int m = 0; m < MF; ++m) {
        const int row = wr * (BM / 2) + m * 16 + frow;
        const int slot = (kk * 4 + kgrp) ^ (row & 7);
        af[m] = *(const bf16x8*)&As[cur * ABUF + row * 64 + slot * 8];
      }
      __builtin_amdgcn_s_setprio(1);
#pragma unroll
      for (int m = 0; m < MF; ++m)
#pragma unroll
        for (int n = 0; n < NF; ++n)
          acc[m][n] = __builtin_amdgcn_mfma_f32_16x16x32_bf16(af[m], bq[n], acc[m][n], 0, 0, 0);
      __builtin_amdgcn_s_setprio(0);
    }
  }

  const int r0 = m0 + wr * (BM / 2) + 4 * kgrp;
  const int c0 = n0 + wc * (BN / 4) + frow;
#pragma unroll
  for (int n = 0; n < NF; ++n) {
    const int cc = c0 + n * 16;
    const float bv = bias[(size_t)e * N + cc];
#pragma unroll
    for (int m = 0; m < MF; ++m) {
#pragma unroll
      for (int r = 0; r < 4; ++r) {
        float v = acc[m][n][r] + bv;
        if (RELU) v = fmaxf(v, 0.f);
        C[((size_t)e * M + (r0 + m * 16 + r)) * N + cc] = f2bf(v);
      }
    }
  }
}

// ========== 8-phase 256x256 grouped GEMM, ledger-corrected (GEMM1 experiment) ==========
// Quadrant order (0,0),(1,0),(0,1),(1,1); all fragments held. Stages: ph1 B(t+1)h1,
// ph3 A(t+2)h0, ph4 A(t+2)h1+B(t+2)h0. Steady-state vmcnt(6) at ph4 only (3 half-tiles
// in flight). Hazards: A[c] reads drain at ph2-close, B[c] h0 reads at ph3-close.
template<bool RELU>
__global__ __launch_bounds__(512, 2) void gemm8p(
    const unsigned short* __restrict__ A,   // (E, M, K) bf16
    const unsigned short* __restrict__ Bt,  // (E, N, K) bf16
    const float* __restrict__ bias,         // (E, N)
    unsigned short* __restrict__ C,         // (E, M, N) bf16
    const int* __restrict__ kept,
    int M, int N, int K, int mt, int nt, int nwg)
{
  __shared__ __attribute__((aligned(16))) unsigned short As[2 * 16384];
  __shared__ __attribute__((aligned(16))) unsigned short Bs[2 * 16384];
  const int tid = threadIdx.x, lane = tid & 63, wave = tid >> 6;
  const int wr = wave >> 2, wc = wave & 3;
  const int frow = lane & 15, kgrp = lane >> 4;

  int wg = (int)blockIdx.x;
  wg = (wg & 7) * (nwg >> 3) + (wg >> 3);
  const int ntpe = mt * nt;
  const int e = wg / ntpe, rr = wg % ntpe;
  const int m0 = (rr / nt) * 256;
  const int n0 = (rr % nt) * 256;
  if (m0 >= kept[e]) return;

  const unsigned short* Ae = A  + (size_t)e * M * K + (size_t)m0 * K;
  const unsigned short* Be = Bt + (size_t)e * N * K + (size_t)n0 * K;

  const int srow = tid >> 3;
  const int scol = ((tid & 7) ^ (srow & 7)) * 8;

  // one half-tile = 128 rows x 64 k = 2 gload_lds per thread
  auto stA = [&](int t, int h) {
    const int c = t & 1, k0 = t * 64;
#pragma unroll
    for (int i = 0; i < 2; ++i)
      GLD16(Ae + (size_t)(h * 128 + i * 64 + srow) * K + (k0 + scol),
            &As[c * 16384 + (h * 128 + i * 64) * 64 + tid * 8]);
  };
  auto stB = [&](int t, int h) {
    const int c = t & 1, k0 = t * 64;
#pragma unroll
    for (int i = 0; i < 2; ++i)
      GLD16(Be + (size_t)(h * 128 + i * 64 + srow) * K + (k0 + scol),
            &Bs[c * 16384 + (h * 128 + i * 64) * 64 + tid * 8]);
  };
  auto rdA = [&](bf16x8* dst, int c, int mh) {   // 8 ds_read_b128
#pragma unroll
    for (int m = 0; m < 4; ++m) {
      const int row = wr * 128 + mh * 64 + m * 16 + frow;
#pragma unroll
      for (int kk = 0; kk < 2; ++kk)
        dst[m * 2 + kk] = *(const bf16x8*)
          &As[c * 16384 + row * 64 + (((kk * 4 + kgrp) ^ (row & 7)) * 8)];
    }
  };
  auto rdB = [&](bf16x8* dst, int c, int nh) {   // 4 ds_read_b128
#pragma unroll
    for (int n = 0; n < 2; ++n) {
      const int row = wc * 64 + nh * 32 + n * 16 + frow;
#pragma unroll
      for (int kk = 0; kk < 2; ++kk)
        dst[n * 2 + kk] = *(const bf16x8*)
          &Bs[c * 16384 + row * 64 + (((kk * 4 + kgrp) ^ (row & 7)) * 8)];
    }
  };

  f32x4 acc[8][4];
#pragma unroll
  for (int m = 0; m < 8; ++m)
#pragma unroll
    for (int n = 0; n < 4; ++n) acc[m][n] = (f32x4){0.f, 0.f, 0.f, 0.f};

  bf16x8 af0[8], af1[8], bq0[4], bq1[4];
  auto mfmaQ = [&](int mh, int nh, bf16x8* af, bf16x8* bq) {  // 16 MFMA
#pragma unroll
    for (int m = 0; m < 4; ++m)
#pragma unroll
      for (int n = 0; n < 2; ++n)
#pragma unroll
        for (int kk = 0; kk < 2; ++kk)
          acc[mh * 4 + m][nh * 2 + n] = __builtin_amdgcn_mfma_f32_16x16x32_bf16(
              af[m * 2 + kk], bq[n * 2 + kk], acc[mh * 4 + m][nh * 2 + n], 0, 0, 0);
  };

  const int nk = K >> 6;   // 16 for GEMM1

  // prologue: tile0 complete + tile1 {Ah0,Ah1,Bh0} in flight (14 loads, wait oldest 8)
  stA(0, 0); stA(0, 1); stB(0, 0); stB(0, 1);
  stA(1, 0); stA(1, 1); stB(1, 0);
  VMW(6);
  BAR();

  for (int t = 0; t < nk; ++t) {
    const int c = t & 1;
    // ---- ph1: read A0[8]+B0[4]; stage B(t+1)h1; MFMA (0,0) ----
    rdA(af0, c, 0);
    rdB(bq0, c, 0);
    if (t + 1 < nk) stB(t + 1, 1);
    LGKM8();
    BAR(); LGKM0(); SB0();
    __builtin_amdgcn_s_setprio(1);
    mfmaQ(0, 0, af0, bq0);
    __builtin_amdgcn_s_setprio(0);
    BAR();
    // ---- ph2: read A1[8]; MFMA (1,0) ----
    rdA(af1, c, 1);
    BAR(); LGKM0(); SB0();
    __builtin_amdgcn_s_setprio(1);
    mfmaQ(1, 0, af1, bq0);
    __builtin_amdgcn_s_setprio(0);
    BAR();
    // ---- ph3: read B1[4]; stage A(t+2)h0 (A[c] reads drained at ph2-close); MFMA (0,1) ----
    rdB(bq1, c, 1);
    if (t + 2 < nk) stA(t + 2, 0);
    BAR(); LGKM0(); SB0();
    __builtin_amdgcn_s_setprio(1);
    mfmaQ(0, 1, af0, bq1);
    __builtin_amdgcn_s_setprio(0);
    BAR();
    // ---- ph4: stage A(t+2)h1 + B(t+2)h0 (B[c]h0 reads drained at ph3-close); MFMA (1,1) ----
    if (t + 2 < nk) { stA(t + 2, 1); stB(t + 2, 0); }
    BAR(); SB0();
    __builtin_amdgcn_s_setprio(1);
    mfmaQ(1, 1, af1, bq1);
    __builtin_amdgcn_s_setprio(0);
    // counted vmcnt: drain through B(t+1)h1 -> tile t+1 fully resident; keep t+2 x3 in flight
    if (t + 2 < nk)      { VMW(6); }
    else if (t + 1 < nk) { VMW(0); }
    if (t + 1 < nk) BAR();
  }

  const int r0 = m0 + wr * 128 + 4 * kgrp;
  const int c0 = n0 + wc * 64 + frow;
#pragma unroll
  for (int nf = 0; nf < 4; ++nf) {
    const int cc = c0 + nf * 16;
    const float bv = bias[(size_t)e * N + cc];
#pragma unroll
    for (int m = 0; m < 8; ++m) {
#pragma unroll
      for (int r = 0; r < 4; ++r) {
        float v = acc[m][nf][r] + bv;
        if (RELU) v = fmaxf(v, 0.f);
        C[((size_t)e * M + (r0 + m * 16 + r)) * N + cc] = f2bf(v);
      }
    }
  }
}

// ---------------- combine ----------------
__global__ __launch_bounds__(256) void combine_kernel(
    const unsigned short* __restrict__ eo, const int* __restrict__ posk,
    const float* __restrict__ wts, const int* __restrict__ topk,
    float* __restrict__ out)
{
  const int t = blockIdx.x;
  const int e0 = topk[2*t], e1 = topk[2*t+1];
  int p0 = posk[2*t], p1 = posk[2*t+1];
  p0 = p0 < CAP - 1 ? p0 : CAP - 1;
  p1 = p1 < CAP - 1 ? p1 : CAP - 1;
  const float w0 = wts[2*t], w1 = wts[2*t+1];
  const ushort4 a = ((const ushort4*)(eo + ((size_t)e0 * CAP + p0) * DM))[threadIdx.x];
  const ushort4 b = ((const ushort4*)(eo + ((size_t)e1 * CAP + p1) * DM))[threadIdx.x];
  f32x4 o;
  o[0] = w0 * bf2f(a.x) + w1 * bf2f(b.x);
  o[1] = w0 * bf2f(a.y) + w1 * bf2f(b.y);
  o[2] = w0 * bf2f(a.z) + w1 * bf2f(b.z);
  o[3] = w0 * bf2f(a.w) + w1 * bf2f(b.w);
  ((f32x4*)(out + (size_t)t * DM))[threadIdx.x] = o;
}

// ---------------- finalize scalars ----------------
__global__ __launch_bounds__(64) void finalize_kernel(
    const float* __restrict__ zP, const int* __restrict__ kept,
    float* __restrict__ outs)
{
  const int lane = threadIdx.x;
  float v[9];
#pragma unroll
  for (int e = 0; e < 9; ++e) {
    float s = 0.f;
    for (int b = 0; b < 8; ++b) s += zP[(lane * 8 + b) * 9 + e];
    v[e] = s;
  }
#pragma unroll
  for (int m = 32; m; m >>= 1)
#pragma unroll
    for (int e = 0; e < 9; ++e) v[e] += __shfl_xor(v[e], m);
  if (lane == 0) {
    const float z = v[0] / (float)N_TOK;
    float total = 0.f;
    for (int e = 0; e < NEXP; ++e) total += (float)kept[e];
    total = fmaxf(total, 1.f);
    float aux = 0.f;
    for (int e = 0; e < NEXP; ++e)
      aux += ((float)kept[e] / total) * (v[1 + e] / (float)N_TOK);
    aux *= (float)NEXP;
    outs[0] = aux;
    outs[1] = z;
    outs[2] = AUX_CO * aux + Z_CO * z;
  }
}

extern "C" void kernel_launch(void* const* d_in, const int* in_sizes, int n_in,
                              void* d_out, int out_size, void* d_ws, size_t ws_size,
                              hipStream_t stream)
{
  const float* x  = (const float*)d_in[0];
  const float* Wr = (const float*)d_in[1];
  const float* W1 = (const float*)d_in[2];
  const float* b1 = (const float*)d_in[3];
  const float* W2 = (const float*)d_in[4];
  const float* b2 = (const float*)d_in[5];
  float* out = (float*)d_out;

  char* p = (char*)d_ws;
  auto alloc = [&](size_t bytes) {
    char* q = p; p += (bytes + 255) & ~(size_t)255; return q;
  };
  unsigned short* W1t = (unsigned short*)alloc((size_t)NEXP * DM * DE * 2);   // (E, DE, DM)
  unsigned short* W2t = (unsigned short*)alloc((size_t)NEXP * DM * DE * 2);   // (E, DM, DE)
  unsigned short* buf = (unsigned short*)alloc((size_t)NEXP * CAP * DM * 2);  // (E, cap, DM)
  unsigned short* h   = (unsigned short*)alloc((size_t)NEXP * CAP * DE * 2);  // (E, cap, DE)
  unsigned short* eo  = (unsigned short*)alloc((size_t)NEXP * CAP * DM * 2);  // (E, cap, DM)
  int*   topk = (int*)alloc((size_t)N_TOK * 2 * 4);
  float* tkw  = (float*)alloc((size_t)N_TOK * 2 * 4);
  int*   posk = (int*)alloc((size_t)N_TOK * 2 * 4);
  float* wts  = (float*)alloc((size_t)N_TOK * 2 * 4);
  int*   inv  = (int*)alloc((size_t)NEXP * CAP * 4);
  int*   kept = (int*)alloc((size_t)NEXP * 4);
  float* zP   = (float*)alloc((size_t)512 * 9 * 4);

  transpose_to_bf16<<<dim3(DE / 32, DM / 32, NEXP), 256, 0, stream>>>(W1, W1t, DM, DE);
  transpose_to_bf16<<<dim3(DM / 32, DE / 32, NEXP), 256, 0, stream>>>(W2, W2t, DE, DM);
  router_kernel<<<512, 256, 0, stream>>>(x, Wr, topk, tkw, zP);
  scan_kernel<<<1, 512, 0, stream>>>((const int2*)topk, (const float2*)tkw, posk, wts, inv, kept);
  dispatch_kernel<<<NEXP * CAP, 256, 0, stream>>>(x, inv, buf);

  // GEMM1 (8-phase experiment): 10m x 16n x 8e = 1280 wgs.
  gemm8p<true><<<1280, 512, 0, stream>>>(buf, W1t, b1, h, kept, CAP, DE, DM, 10, 16, 1280);
  // GEMM2 (proven 2-phase, 128^2, 2 blocks/CU): 20m x 8n x 8e = 1280 wgs.
  gemm2p<128, 128, false><<<1280, 512, 0, stream>>>(
      h, W2t, b2, eo, kept, CAP, DM, DE, 20, 8, 1280);

  combine_kernel<<<N_TOK, 256, 0, stream>>>(eo, posk, wts, topk, out);
  finalize_kernel<<<1, 64, 0, stream>>>(zP, kept, out + (size_t)N_TOK * DM);
}